// Round 12
// baseline (239.465 us; speedup 1.0000x reference)
//
#include <hip/hip_runtime.h>

typedef unsigned int u32;
typedef unsigned short u16;
typedef __bf16 bf16x8 __attribute__((ext_vector_type(8)));
typedef float floatx4 __attribute__((ext_vector_type(4)));
typedef _Float16 f16x4 __attribute__((ext_vector_type(4)));
typedef __fp16 fp16x2 __attribute__((ext_vector_type(2)));

// ---- helpers ----------------------------------------------------------------

// fp32 -> bf16 bits, round-to-nearest-even
__device__ __forceinline__ u16 f2b(float f) {
    u32 u = __float_as_uint(f);
    u = u + 0x7fffu + ((u >> 16) & 1u);
    return (u16)(u >> 16);
}

// pack 4 fp32 -> f16x4 via v_cvt_pkrtz_f16_f32
__device__ __forceinline__ f16x4 pack4h(float a, float b, float c, float d) {
    union { fp16x2 h2[2]; f16x4 h4; } u;
    u.h2[0] = __builtin_amdgcn_cvt_pkrtz(a, b);
    u.h2[1] = __builtin_amdgcn_cvt_pkrtz(c, d);
    return u.h4;
}

// pack 2 fp32 -> u32 of 2 bf16
__device__ __forceinline__ u32 pack2b(float a, float b) {
    return (u32)f2b(a) | ((u32)f2b(b) << 16);
}

// async global->LDS 16B copy (lane-linear LDS dest required)
__device__ __forceinline__ void async_copy16(const void* g, void* l) {
    __builtin_amdgcn_global_load_lds(
        (__attribute__((address_space(1))) u32*)g,
        (__attribute__((address_space(3))) u32*)l, 16, 0, 0);
}

// ---- merged cast kernel -----------------------------------------------------
// x: 2097152 float4 | Wqkv: 786432 | Wproj: 262144  (total 3145728)

__global__ void cast_all_kernel(const float4* __restrict__ x,
                                const float4* __restrict__ wq,
                                const float4* __restrict__ wp,
                                ushort4* __restrict__ xb,
                                ushort4* __restrict__ wqb,
                                ushort4* __restrict__ wpb) {
    int i = blockIdx.x * 256 + threadIdx.x;
    const float4* s;
    ushort4* d;
    int off;
    if (i < 2097152) { s = x; d = xb; off = i; }
    else if (i < 2883584) { s = wq; d = wqb; off = i - 2097152; }
    else { s = wp; d = wpb; off = i - 2883584; }
    float4 v = s[off];
    ushort4 o;
    o.x = f2b(v.x); o.y = f2b(v.y); o.z = f2b(v.z); o.w = f2b(v.w);
    d[off] = o;
}

// ---- unified 128x128 BK=32 GEMM core (round 12) -----------------------------
// 256 threads (4 waves, 2M x 2N), wave tile 64x64, acc[4][4] (64 AGPR),
// 32 KB LDS -> with __launch_bounds__(256,4) targets 16 waves/CU (4 blocks),
// 2x the previous GEMM occupancy. Rationale: attn's round-9 win and the
// proj128≈TOKFEAT2 null both show waves/CU is the controlling variable for
// hiding barrier/latency stalls (m114); all 8-waves/CU GEMM variants plateau
// at 850-900 TF with ~50% neither-pipe idle.
//
// LDS tile [128 rows][4 chunks of 16B]; slot (r,c) holds global chunk
// c ^ s(r), s(r) = (r&3)^((r>>2)&3). Read: chunk quad of row rr lives at
// slot quad^s(rr); for rr = base16k + l16, s(rr) = (l16&3)^((l16>>2)&3) is
// per-lane constant (bases are multiples of 16). Bank audit: 16 l16-lanes
// per quad map 2-way (free, m136). Write side: thread t (wave w, lane l)
// covers slot (r = i*64+w*16+(l>>2), c = l&3), LDS addr = wave-uniform base
// + l*16 (gload_lds-legal); global source chunk = (l&3)^((l>>2)&3)^((l>>4)&3)
// = c ^ s(r) (same involution, rule #21).
//
// Ledger: per iter j: reads(8 ds_read_b128) -> barrier#1 -> stage tile j+2
// into current parity (4 loads; same read-issue/stage-write separation as
// rounds 2-11) -> 16 MFMA (compiler lgkm-waits) -> vmcnt(4) (leaves exactly
// j+2's 4 -> j+1 landed) -> barrier#2. Prologue: tiles 0,1 = 8 loads,
// vmcnt(4) -> tile0 landed. Drain vmcnt(0) at j >= NT-2.

// stage one [128 rows][32 cols] bf16 tile, row stride 1024 u16, 256 threads
__device__ __forceinline__ void stage_tile32(const u16* __restrict__ src,
                                             int row0, int k0,
                                             u16* ldsbase, int t) {
    const int l = t & 63;
    const int w = t >> 6;
    const int swzc = (((l & 3) ^ ((l >> 2) & 3) ^ ((l >> 4) & 3))) * 8;
#pragma unroll
    for (int i = 0; i < 2; ++i) {
        const int r = i * 64 + w * 16 + (l >> 2);
        async_copy16(src + (size_t)(row0 + r) * 1024 + k0 + swzc,
                     ldsbase + r * 32 + (l & 3) * 8);
    }
}

#define GEMM128(Asrc, Bsrc, M0, N0)                                            \
    constexpr int NT = 32;                                                     \
    const int t = threadIdx.x;                                                 \
    const int lane = t & 63;                                                   \
    const int quad = lane >> 4, l16 = lane & 15;                               \
    const int wave = t >> 6;                                                   \
    const int wm = wave >> 1, wn = wave & 1;                                   \
    const int m0 = (M0), n0 = (N0);                                            \
    const int cswz = ((quad ^ (l16 & 3) ^ ((l16 >> 2) & 3))) * 8;              \
    u16* const Ab0 = lds;                 /* [128][32] = 8 KB */               \
    u16* const Ab1 = lds + 4096;                                               \
    u16* const Bb0 = lds + 8192;                                               \
    u16* const Bb1 = lds + 12288;                                              \
    floatx4 acc[4][4];                                                         \
    _Pragma("unroll")                                                          \
    for (int i = 0; i < 4; ++i)                                                \
        _Pragma("unroll")                                                      \
        for (int jj = 0; jj < 4; ++jj) acc[i][jj] = floatx4{0.f,0.f,0.f,0.f};  \
    /* prologue: tiles 0,1 = 8 loads/thread */                                 \
    stage_tile32(Asrc, m0, 0,  Ab0, t);                                        \
    stage_tile32(Bsrc, n0, 0,  Bb0, t);                                        \
    stage_tile32(Asrc, m0, 32, Ab1, t);                                        \
    stage_tile32(Bsrc, n0, 32, Bb1, t);                                        \
    asm volatile("s_waitcnt vmcnt(4)" ::: "memory");                           \
    __builtin_amdgcn_s_barrier();                                              \
    _Pragma("unroll 2")                                                        \
    for (int j = 0; j < NT; ++j) {                                             \
        u16* const A = (j & 1) ? Ab1 : Ab0;                                    \
        u16* const B = (j & 1) ? Bb1 : Bb0;                                    \
        const int k2 = (j + 2) << 5;                                           \
        bf16x8 af[4], bf[4];                                                   \
        _Pragma("unroll")                                                      \
        for (int fi = 0; fi < 4; ++fi)                                         \
            af[fi] = *(const bf16x8*)&A[(wm * 64 + fi * 16 + l16) * 32 + cswz];\
        _Pragma("unroll")                                                      \
        for (int fj = 0; fj < 4; ++fj)                                         \
            bf[fj] = *(const bf16x8*)&B[(wn * 64 + fj * 16 + l16) * 32 + cswz];\
        __builtin_amdgcn_s_barrier();                                          \
        if (j + 2 < NT) {                                                      \
            stage_tile32(Asrc, m0, k2, A, t);                                  \
            stage_tile32(Bsrc, n0, k2, B, t);                                  \
        }                                                                      \
        __builtin_amdgcn_s_setprio(1);                                         \
        _Pragma("unroll")                                                      \
        for (int fi = 0; fi < 4; ++fi)                                         \
            _Pragma("unroll")                                                  \
            for (int fj = 0; fj < 4; ++fj)                                     \
                acc[fi][fj] = __builtin_amdgcn_mfma_f32_16x16x32_bf16(         \
                    af[fi], bf[fj], acc[fi][fj], 0, 0, 0);                     \
        __builtin_amdgcn_s_setprio(0);                                         \
        if (j < NT - 2) {                                                      \
            asm volatile("s_waitcnt vmcnt(4)" ::: "memory");                   \
        } else {                                                               \
            asm volatile("s_waitcnt vmcnt(0)" ::: "memory");                   \
        }                                                                      \
        __builtin_amdgcn_s_barrier();                                          \
    }

// ---- fused QKV GEMM: 1536 blocks, uniform shape -> continuous backfill ------
// blocks 0..1023: qk role (feat tile bx = f&15 -> per-XCD W panels, token
// tile by = f>>4). blocks 1024..1535: V role (token tile, feat tile).

__global__ __launch_bounds__(256, 4) void gemm_qkv_fused(
    const u16* __restrict__ X, const u16* __restrict__ W,
    u16* __restrict__ qkvsep, u16* __restrict__ Vt) {
    __shared__ u16 lds[16384];           // 32 KiB
    const int f = blockIdx.x;
    if (f < 1024) {
        // A = Wqkv rows (feats 0..2047), B = X rows (tokens)
        GEMM128(W, X, (f & 15) * 128, (f >> 4) * 128)
        // epilogue: 8-B packed stores, natural qkvsep layout
#pragma unroll
        for (int fi = 0; fi < 4; ++fi) {
            const int feat = m0 + wm * 64 + fi * 16 + quad * 4;
            const int tsel = feat >> 10, h = (feat >> 6) & 15, e = feat & 63;
#pragma unroll
            for (int fj = 0; fj < 4; ++fj) {
                const int token = n0 + wn * 64 + fj * 16 + l16;
                const int b = token >> 10, nn = token & 1023;
                u16* dst = qkvsep +
                    ((((size_t)tsel * 8 + b) * 16 + h) * 1024 + nn) * 64 + e;
                *(uint2*)dst = make_uint2(pack2b(acc[fi][fj][0], acc[fi][fj][1]),
                                          pack2b(acc[fi][fj][2], acc[fi][fj][3]));
            }
        }
    } else {
        const int f2 = f - 1024;         // 0..511: 64 token-tiles x 8 feat-tiles
        const u16* Wv = W + (size_t)2048 * 1024;   // V rows of Wqkv
        // A = X rows (tokens), B = Wv rows (V feats)
        GEMM128(X, Wv, (f2 >> 3) * 128, (f2 & 7) * 128)
        // epilogue: regs = 4 consecutive tokens -> pack4h -> 8B store Vt[e][n]
#pragma unroll
        for (int fi = 0; fi < 4; ++fi) {
            const int token = m0 + wm * 64 + fi * 16 + quad * 4;
            const int b = token >> 10, nn = token & 1023;
#pragma unroll
            for (int fj = 0; fj < 4; ++fj) {
                const int vfeat = n0 + wn * 64 + fj * 16 + l16;   // 0..1023
                const int h = vfeat >> 6, e = vfeat & 63;
                f16x4 v = pack4h(acc[fi][fj][0], acc[fi][fj][1],
                                 acc[fi][fj][2], acc[fi][fj][3]);
                *(f16x4*)(Vt + (((size_t)(b * 16 + h) * 64 + e) * 1024 + nn)) = v;
            }
        }
    }
}

// ---- GEMM 2: out = O @ Wproj^T + bias, fp32 out -----------------------------
// 512 blocks (64 token-tiles x 8 feat-tiles), same unified core.

__global__ __launch_bounds__(256, 4) void gemm_proj_kernel(
    const u16* __restrict__ Ob, const u16* __restrict__ W,
    const float* __restrict__ bias, float* __restrict__ out) {
    __shared__ u16 lds[16384];           // 32 KiB
    const int f = blockIdx.x;
    GEMM128(Ob, W, (f >> 3) * 128, (f & 7) * 128)
#pragma unroll
    for (int fi = 0; fi < 4; ++fi) {
        const int token = m0 + wm * 64 + fi * 16 + quad * 4;
#pragma unroll
        for (int fj = 0; fj < 4; ++fj) {
            const int feat = n0 + wn * 64 + fj * 16 + l16;
            const float bn = bias[feat];
#pragma unroll
            for (int r = 0; r < 4; ++r)
                out[(size_t)(token + r) * 1024 + feat] = acc[fi][fj][r] + bn;
        }
    }
}

// ---- MFMA flash attention, S^T formulation, in-register P -------------------
// Round-9 structure (validated): 8 waves/block, 2 q-sets/wave, K/V staged once
// per block, T14 reg-prefetch + LDS dbuf + T5 setprio + pkrtz.

__global__ __launch_bounds__(512, 2) void attn_mfma_kernel(
    const u16* __restrict__ qkv, const u16* __restrict__ Vt,
    u16* __restrict__ O) {
    __shared__ u16 sK[2][64 * 72];
    __shared__ u16 sV[2][64 * 72];   // f16 payload, [e][n] tile

    const int t = threadIdx.x;
    const int wave = t >> 6, lane = t & 63;
    const int quad = lane >> 4, l16 = lane & 15;
    const int id = blockIdx.x;                 // 0..511
    const int bh = (id & 7) + 8 * ((id >> 3) & 15);
    const int qb = id >> 7;                    // 0..3 (256 q-rows each)
    const size_t headoff = (size_t)bh * (1024 * 64);
    const u16* Qp = qkv + headoff;
    const u16* Kp = qkv + (size_t)128 * 1024 * 64 + headoff;
    const u16* Vtp = Vt + headoff;

    // per-thread staging coordinates: 512 threads = 64 rows x 8 chunks
    const int srow = t >> 3, sc8 = (t & 7) * 8;

    // Q B-frags for this wave's two 16-row q-sets (lane l16 = query)
    bf16x8 qf0[2], qf1[2];
#pragma unroll
    for (int qs = 0; qs < 2; ++qs) {
        const u16* qrow =
            Qp + (size_t)(qb * 256 + wave * 32 + qs * 16 + l16) * 64 + quad * 8;
        qf0[qs] = *(const bf16x8*)(qrow);
        qf1[qs] = *(const bf16x8*)(qrow + 32);
    }

    float l_part[2];
    floatx4 accO[2][4];   // [qs][et], O^T layout: lane=query, reg=e
#pragma unroll
    for (int qs = 0; qs < 2; ++qs) {
        l_part[qs] = 0.f;
#pragma unroll
        for (int et = 0; et < 4; ++et) accO[qs][et] = floatx4{0.f, 0.f, 0.f, 0.f};
    }

    // exp2 domain: p = 2^(s*0.125*log2e - 8*log2e)
    const float S2 = 0.18033688f;    // 0.125 * log2(e)
    const float B2 = -11.5415603f;   // -8 * log2(e)

    f16x4 pf[2][4];   // [qs][nt] P fragments (B-operand of PV)

    // prefetch tile 0 into registers (1 K chunk + 1 V chunk per thread)
    uint4 rk, rv;
    rk = *(const uint4*)(Kp + (size_t)srow * 64 + sc8);
    rv = *(const uint4*)(Vtp + (size_t)srow * 1024 + sc8);

    for (int kb = 0; kb < 16; ++kb) {
        const int p = kb & 1;
        // write staged registers to LDS (vmcnt wait on prefetch is here,
        // but the loads were issued a full compute-phase ago)
        *(uint4*)(&sK[p][srow * 72 + sc8]) = rk;
        *(uint4*)(&sV[p][srow * 72 + sc8]) = rv;
        // issue next tile's global loads (complete under this tile's compute)
        if (kb < 15) {
            const int kn = (kb + 1) * 64;
            rk = *(const uint4*)(Kp + (size_t)(kn + srow) * 64 + sc8);
            rv = *(const uint4*)(Vtp + (size_t)srow * 1024 + kn + sc8);
        }
        __syncthreads();

        // K A-frags (lane l16 = key), held across q-sets
        bf16x8 kf0[4], kf1[4];
#pragma unroll
        for (int nt = 0; nt < 4; ++nt) {
            const u16* krow = sK[p] + (nt * 16 + l16) * 72 + quad * 8;
            kf0[nt] = *(const bf16x8*)(krow);
            kf1[nt] = *(const bf16x8*)(krow + 32);
        }

        // Phase A: S^T = K Q^T, exp2, pack P into registers
#pragma unroll
        for (int qs = 0; qs < 2; ++qs) {
            float lsum = 0.f;
#pragma unroll
            for (int nt = 0; nt < 4; ++nt) {
                floatx4 z = {0.f, 0.f, 0.f, 0.f};
                z = __builtin_amdgcn_mfma_f32_16x16x32_bf16(kf0[nt], qf0[qs], z, 0, 0, 0);
                z = __builtin_amdgcn_mfma_f32_16x16x32_bf16(kf1[nt], qf1[qs], z, 0, 0, 0);
                float p0 = __builtin_amdgcn_exp2f(fmaf(z[0], S2, B2));
                float p1 = __builtin_amdgcn_exp2f(fmaf(z[1], S2, B2));
                float p2 = __builtin_amdgcn_exp2f(fmaf(z[2], S2, B2));
                float p3 = __builtin_amdgcn_exp2f(fmaf(z[3], S2, B2));
                lsum += (p0 + p1) + (p2 + p3);
                pf[qs][nt] = pack4h(p0, p1, p2, p3);
            }
            l_part[qs] += lsum;
        }

        // Phase B: O^T += V^T P  (A = V^T f16 frags, B = P from registers)
        __builtin_amdgcn_s_setprio(1);
#pragma unroll
        for (int et = 0; et < 4; ++et) {
#pragma unroll
            for (int nt = 0; nt < 4; ++nt) {
                f16x4 vf = *(const f16x4*)(sV[p] + (et * 16 + l16) * 72 +
                                           nt * 16 + quad * 4);
#pragma unroll
                for (int qs = 0; qs < 2; ++qs)
                    accO[qs][et] = __builtin_amdgcn_mfma_f32_16x16x16f16(
                        vf, pf[qs][nt], accO[qs][et], 0, 0, 0);
            }
        }
        __builtin_amdgcn_s_setprio(0);
    }

    // epilogue: l = sum over quads; O^T lane=query holds e=quad*4+r per et.
    const int b = bh >> 4, h = bh & 15;
#pragma unroll
    for (int qs = 0; qs < 2; ++qs) {
        float l = l_part[qs];
        l += __shfl_xor(l, 16);
        l += __shfl_xor(l, 32);
        const float inv = 1.f / l;
        const int q = qb * 256 + wave * 32 + qs * 16 + l16;
        u16* orow = O + (size_t)(b * 1024 + q) * 1024 + h * 64 + quad * 4;
#pragma unroll
        for (int et = 0; et < 4; ++et) {
            u32 r0 = pack2b(accO[qs][et][0] * inv, accO[qs][et][1] * inv);
            u32 r1 = pack2b(accO[qs][et][2] * inv, accO[qs][et][3] * inv);
            *(uint2*)(orow + et * 16) = make_uint2(r0, r1);
        }
    }
}

// ---- launch -----------------------------------------------------------------

extern "C" void kernel_launch(void* const* d_in, const int* in_sizes, int n_in,
                              void* d_out, int out_size, void* d_ws, size_t ws_size,
                              hipStream_t stream) {
    const float* x     = (const float*)d_in[0];   // [8,1024,1024]
    const float* Wqkv  = (const float*)d_in[1];   // [3072,1024]
    const float* Wproj = (const float*)d_in[2];   // [1024,1024]
    const float* bproj = (const float*)d_in[3];   // [1024]
    float* out = (float*)d_out;

    char* ws = (char*)d_ws;
    u16* xb     = (u16*)(ws);                            // 16 MiB
    u16* wqkvb  = (u16*)(ws + (16ull << 20));            // 6 MiB
    u16* wprojb = (u16*)(ws + (22ull << 20));            // 2 MiB
    u16* qkvsep = (u16*)(ws + (24ull << 20));            // Q,K: [2][8][16][1024][64]
    u16* vtb    = (u16*)(ws + (72ull << 20));            // 16 MiB f16: [8][16][64][1024]
    u16* Ob     = (u16*)(ws + (88ull << 20));            // 16 MiB: [8][1024][1024]

    cast_all_kernel<<<12288, 256, 0, stream>>>(
        (const float4*)x, (const float4*)Wqkv, (const float4*)Wproj,
        (ushort4*)xb, (ushort4*)wqkvb, (ushort4*)wprojb);

    gemm_qkv_fused<<<1536, 256, 0, stream>>>(xb, wqkvb, qkvsep, vtb);
    attn_mfma_kernel<<<512, 512, 0, stream>>>(qkvsep, vtb, Ob);
    gemm_proj_kernel<<<512, 256, 0, stream>>>(Ob, wprojb, bproj, out);
}